// Round 9
// baseline (4266.446 us; speedup 1.0000x reference)
//
#include <hip/hip_runtime.h>
#include <hip/hip_fp16.h>
#include <math.h>

// R9 = R7 (proven, unchanged real kernels) + phase-attribution PROBES.
// Probes replicate the scan's per-step structure piecewise, write only to
// d_ws (gated on ws_size), and appear as separate rocprof dispatches:
//   probe01(drain=0): sync skeleton (poll+barriers+stores+vote+publish)
//   probe01(drain=1): + vmcnt(0) drain
//   probe2:           + staging (L2-warm fixed xs slice, pkrtz, LDS)
//   probe3:           full replica minus the true produce->consume dependency
// real_scan - probe3 = dependency/data-arrival residual.

#define TSTEPS 256

typedef _Float16 f16x8 __attribute__((ext_vector_type(8)));
typedef _Float16 f16x4 __attribute__((ext_vector_type(4)));
typedef __fp16 h16x2 __attribute__((ext_vector_type(2)));
typedef __fp16 h16x4 __attribute__((ext_vector_type(4)));
typedef float f32x4 __attribute__((ext_vector_type(4)));
typedef float vf4 __attribute__((ext_vector_type(4)));
typedef float vf2 __attribute__((ext_vector_type(2)));

#define GSTR 656          // f16 units per kstep block (1312 B)
// LDS: Ahi 32*1312 = 41984 @0 ; Alo @41984 ; red [64][17]f32 = 4352 @83968 ;
//      su  [16][68]f32 = 4352 @88320 ; done u32 @92672
#define SCAN_LDS 92704

// ---------------- real scan (R7, proven: 1368 us, absmax 0.125) -------------
__global__ __launch_bounds__(512, 2) void scan_kernel(
    const float* __restrict__ x0, const float* __restrict__ ss,
    const float* __restrict__ us, const float* __restrict__ Bsm,
    const float* __restrict__ Wm, const float* __restrict__ bv,
    float* __restrict__ xs, unsigned* __restrict__ flags)
{
  extern __shared__ char smem[];
  _Float16* Ahi = (_Float16*)smem;
  _Float16* Alo = (_Float16*)(smem + 41984);
  float* red = (float*)(smem + 83968);
  float* su  = (float*)(smem + 88320);
  unsigned* done = (unsigned*)(smem + 92672);

  const int tid  = threadIdx.x;
  const int lane = tid & 63;
  const int wave = tid >> 6;
  const int n    = wave & 3;
  const int kh   = wave >> 2;
  const int bid  = blockIdx.x;
  const int jb   = bid >> 3;
  const int c    = (bid & 7) + 8 * (jb >> 4);
  const int s    = jb & 15;
  const int row0 = c * 16;
  const int col0 = s * 64;

  const int l15 = lane & 15;
  const int lg  = lane >> 4;
  const int jcol = col0 + n * 16 + l15;

  f16x8 Whi[16], Wlo[16];
#pragma unroll
  for (int i = 0; i < 16; ++i) {
    int g = kh * 16 + i;
    const float* p = Wm + (size_t)jcol * 1024 + 32 * g + 8 * lg;
    vf4 v0 = *(const vf4*)p, v1 = *(const vf4*)(p + 4);
#pragma unroll
    for (int e = 0; e < 4; ++e) {
      float va = v0[e]; _Float16 h = (_Float16)va;
      Whi[i][e] = h; Wlo[i][e] = (_Float16)(va - (float)h);
      float vb = v1[e]; _Float16 h2 = (_Float16)vb;
      Whi[i][e + 4] = h2; Wlo[i][e + 4] = (_Float16)(vb - (float)h2);
    }
  }

  const float bcol = bv[jcol];

  f32x4 xold = {0.f, 0.f, 0.f, 0.f};
  if (kh == 0) {
#pragma unroll
    for (int i = 0; i < 4; ++i)
      xold[i] = x0[(size_t)(row0 + lg * 4 + i) * 1024 + jcol];
  }

  {
    int i0 = tid * 2; int r = i0 >> 6, cc = i0 & 63;
    *(vf2*)&xs[((size_t)(row0 + r) * TSTEPS) * 1024 + col0 + cc] =
        *(const vf2*)&x0[(size_t)(row0 + r) * 1024 + col0 + cc];
  }
  if (tid == 0) *done = 0;
  __syncthreads();

  const int srow = tid >> 5;
  const int spos = tid & 31;
  const int skk  = (tid & 7) * 4;

  unsigned* const myslot = flags + c * 16 + s;
  unsigned* const pollp  = flags + c * 16 + l15;

  for (int t = 0; t < TSTEPS - 1; ++t) {
    if (t > 0) {
      if (wave == 4) {
        unsigned v;
        do {
          v = __hip_atomic_load(pollp, __ATOMIC_RELAXED, __HIP_MEMORY_SCOPE_AGENT);
        } while (!__all((int)(v >= (unsigned)t)));
      }
      __syncthreads();
    }
    asm volatile("" ::: "memory");

    {
      const float* rb = (t == 0)
          ? (x0 + (size_t)(row0 + srow) * 1024)
          : (xs + ((size_t)(row0 + srow) * TSTEPS + t) * 1024);
#pragma unroll
      for (int j = 0; j < 8; ++j) {
        int k = spos * 4 + j * 128;
        vf4 v = *(const vf4*)(rb + k);
        int g = (spos >> 3) + 4 * j;
        h16x2 h01 = __builtin_amdgcn_cvt_pkrtz(v[0], v[1]);
        h16x2 h23 = __builtin_amdgcn_cvt_pkrtz(v[2], v[3]);
        h16x2 l01 = __builtin_amdgcn_cvt_pkrtz(v[0] - (float)h01[0],
                                               v[1] - (float)h01[1]);
        h16x2 l23 = __builtin_amdgcn_cvt_pkrtz(v[2] - (float)h23[0],
                                               v[3] - (float)h23[1]);
        h16x4 h4 = __builtin_shufflevector(h01, h23, 0, 1, 2, 3);
        h16x4 l4 = __builtin_shufflevector(l01, l23, 0, 1, 2, 3);
        int a = g * GSTR + srow * 40 + skk;
        *(h16x4*)(Ahi + a) = h4;
        *(h16x4*)(Alo + a) = l4;
      }
      if (s == 0 && tid < 256) {
        int r = tid >> 4, c0 = (tid & 15) * 4;
        vf4 a = *(const vf4*)(ss + ((size_t)(row0 + r) * TSTEPS + t) * 64 + c0);
        vf4 b = *(const vf4*)(us + ((size_t)(row0 + r) * TSTEPS + t) * 64 + c0);
        vf4 m = a + b;
        *(vf4*)&su[r * 68 + c0] = m;
      }
    }
    __syncthreads();

    f32x4 a0 = {0.f,0.f,0.f,0.f}, a1 = {0.f,0.f,0.f,0.f}, a2 = {0.f,0.f,0.f,0.f};
#pragma unroll
    for (int i = 0; i < 16; ++i) {
      int g = kh * 16 + i;
      const int ab = g * GSTR + l15 * 40 + 8 * lg;
      f16x8 ah = *(const f16x8*)(Ahi + ab);
      f16x8 al = *(const f16x8*)(Alo + ab);
      a0 = __builtin_amdgcn_mfma_f32_16x16x32_f16(ah, Whi[i], a0, 0, 0, 0);
      a1 = __builtin_amdgcn_mfma_f32_16x16x32_f16(ah, Wlo[i], a1, 0, 0, 0);
      a2 = __builtin_amdgcn_mfma_f32_16x16x32_f16(al, Whi[i], a2, 0, 0, 0);
    }
    if (kh == 1) {
#pragma unroll
      for (int i = 0; i < 4; ++i)
        red[(n * 16 + lg * 4 + i) * 17 + l15] = a0[i] + a1[i] + a2[i];
    }
    __syncthreads();

    if (kh == 0) {
#pragma unroll
      for (int i = 0; i < 4; ++i) {
        int r = lg * 4 + i;
        float z = a0[i] + a1[i] + a2[i] + red[(n * 16 + r) * 17 + l15] + bcol;
        if (s == 0) z += su[r * 68 + n * 16 + l15];
        float e = exp2f(z * 2.885390081777927f);
        float rc = __builtin_amdgcn_rcpf(e + 1.0f);
        float xnew = fmaf(0.9f, xold[i], fmaf(-0.2f, rc, 0.1f));
        xold[i] = xnew;
        __hip_atomic_store(&xs[((size_t)(row0 + r) * TSTEPS + (t + 1)) * 1024 + jcol],
                           xnew, __ATOMIC_RELAXED, __HIP_MEMORY_SCOPE_AGENT);
      }
      asm volatile("s_waitcnt vmcnt(0)" ::: "memory");
      if (lane == 0) {
        unsigned old = atomicAdd(done, 1u);
        if (old == 4u * (unsigned)t + 3u)
          __hip_atomic_store(myslot, (unsigned)(t + 1), __ATOMIC_RELAXED,
                             __HIP_MEMORY_SCOPE_AGENT);
      }
    }
  }
}

// ---------------- readout (unchanged) ----------------
__global__ __launch_bounds__(256, 2) void y_kernel(
    const float* __restrict__ xs, const float* __restrict__ Wy,
    const float* __restrict__ by, float* __restrict__ ys)
{
  __shared__ _Float16 Af[64][72];
  __shared__ _Float16 Bf[64][72];
  const int tid = threadIdx.x;
  const int lane = tid & 63;
  const int wave = tid >> 6;
  const int l15 = lane & 15, lg = lane >> 4;
  const size_t bm = (size_t)blockIdx.x * 64;
  const int bn = blockIdx.y * 64;

  f32x4 acc[4];
#pragma unroll
  for (int q = 0; q < 4; ++q) acc[q] = (f32x4){0.f, 0.f, 0.f, 0.f};

  for (int kc = 0; kc < 16; ++kc) {
#pragma unroll
    for (int p = 0; p < 4; ++p) {
      int fi = tid + 256 * p;
      int r = fi >> 4, kq = fi & 15;
      vf4 va = *(const vf4*)(xs + (bm + r) * 1024 + kc * 64 + kq * 4);
      h16x2 a01 = __builtin_amdgcn_cvt_pkrtz(va[0], va[1]);
      h16x2 a23 = __builtin_amdgcn_cvt_pkrtz(va[2], va[3]);
      *(h16x4*)(&Af[r][kq * 4]) = __builtin_shufflevector(a01, a23, 0, 1, 2, 3);
      vf4 vb = *(const vf4*)(Wy + (size_t)(bn + r) * 1024 + kc * 64 + kq * 4);
      h16x2 b01 = __builtin_amdgcn_cvt_pkrtz(vb[0], vb[1]);
      h16x2 b23 = __builtin_amdgcn_cvt_pkrtz(vb[2], vb[3]);
      *(h16x4*)(&Bf[r][kq * 4]) = __builtin_shufflevector(b01, b23, 0, 1, 2, 3);
    }
    __syncthreads();
#pragma unroll
    for (int ks = 0; ks < 2; ++ks) {
      int k0 = ks * 32 + 8 * lg;
      f16x8 af = *(const f16x8*)(&Af[wave * 16 + l15][k0]);
#pragma unroll
      for (int nt = 0; nt < 4; ++nt) {
        f16x8 bf = *(const f16x8*)(&Bf[nt * 16 + l15][k0]);
        acc[nt] = __builtin_amdgcn_mfma_f32_16x16x32_f16(af, bf, acc[nt], 0, 0, 0);
      }
    }
    __syncthreads();
  }
#pragma unroll
  for (int nt = 0; nt < 4; ++nt) {
#pragma unroll
    for (int i = 0; i < 4; ++i) {
      size_t grow = bm + wave * 16 + lg * 4 + i;
      int gcol = bn + nt * 16 + l15;
      ys[grow * 256 + gcol] = acc[nt][i] + by[gcol];
    }
  }
}

// ---------------- probes (write only d_ws; diagnostic dispatches) -----------
// d_ws words: real flags [0..255]; probe slots at slotoff 256/512/768/1024;
// dummy strips at word 4096 + bid*1024 (1 MB).

__global__ __launch_bounds__(512, 2) void probe01_kernel(
    unsigned* __restrict__ flags, int slotoff, int do_drain)
{
  extern __shared__ char smem[];
  unsigned* done = (unsigned*)(smem + 92672);
  const int tid = threadIdx.x, lane = tid & 63, wave = tid >> 6;
  const int n = wave & 3, kh = wave >> 2;
  const int bid = blockIdx.x, jb = bid >> 3;
  const int c = (bid & 7) + 8 * (jb >> 4), s = jb & 15;
  const int l15 = lane & 15, lg = lane >> 4;
  unsigned* slotb = flags + slotoff;
  unsigned* myslot = slotb + c * 16 + s;
  unsigned* pollp  = slotb + c * 16 + l15;
  unsigned* dummy  = flags + 4096 + bid * 1024;
  if (tid == 0) *done = 0u;
  __syncthreads();
  for (int t = 0; t < TSTEPS - 1; ++t) {
    if (t > 0) {
      if (wave == 4) {
        unsigned v;
        do {
          v = __hip_atomic_load(pollp, __ATOMIC_RELAXED, __HIP_MEMORY_SCOPE_AGENT);
        } while (!__all((int)(v >= (unsigned)t)));
      }
      __syncthreads();  // barP
    }
    __syncthreads();    // barA
    __syncthreads();    // barB
    if (kh == 0) {
#pragma unroll
      for (int i = 0; i < 4; ++i)
        __hip_atomic_store(dummy + (lg * 4 + i) * 64 + n * 16 + l15, (unsigned)t,
                           __ATOMIC_RELAXED, __HIP_MEMORY_SCOPE_AGENT);
      if (do_drain) asm volatile("s_waitcnt vmcnt(0)" ::: "memory");
      if (lane == 0) {
        unsigned old = atomicAdd(done, 1u);
        if (old == 4u * (unsigned)t + 3u)
          __hip_atomic_store(myslot, (unsigned)(t + 1), __ATOMIC_RELAXED,
                             __HIP_MEMORY_SCOPE_AGENT);
      }
    }
  }
}

__global__ __launch_bounds__(512, 2) void probe2_kernel(
    const float* __restrict__ x0, const float* __restrict__ ss,
    const float* __restrict__ us, const float* __restrict__ xs,
    unsigned* __restrict__ flags, int slotoff)
{
  extern __shared__ char smem[];
  _Float16* Ahi = (_Float16*)smem;
  _Float16* Alo = (_Float16*)(smem + 41984);
  float* su = (float*)(smem + 88320);
  unsigned* done = (unsigned*)(smem + 92672);
  const int tid = threadIdx.x, lane = tid & 63, wave = tid >> 6;
  const int n = wave & 3, kh = wave >> 2;
  const int bid = blockIdx.x, jb = bid >> 3;
  const int c = (bid & 7) + 8 * (jb >> 4), s = jb & 15;
  const int l15 = lane & 15, lg = lane >> 4;
  const int row0 = c * 16;
  const int srow = tid >> 5, spos = tid & 31, skk = (tid & 7) * 4;
  unsigned* slotb = flags + slotoff;
  unsigned* myslot = slotb + c * 16 + s;
  unsigned* pollp  = slotb + c * 16 + l15;
  unsigned* dummy  = flags + 4096 + bid * 1024;
  if (tid == 0) *done = 0u;
  __syncthreads();
  for (int t = 0; t < TSTEPS - 1; ++t) {
    if (t > 0) {
      if (wave == 4) {
        unsigned v;
        do {
          v = __hip_atomic_load(pollp, __ATOMIC_RELAXED, __HIP_MEMORY_SCOPE_AGENT);
        } while (!__all((int)(v >= (unsigned)t)));
      }
      __syncthreads();
    }
    asm volatile("" ::: "memory");
    {  // staging from FIXED slice t=1 (L2-warm floor)
      const float* rb = xs + ((size_t)(row0 + srow) * TSTEPS + 1) * 1024;
#pragma unroll
      for (int j = 0; j < 8; ++j) {
        int k = spos * 4 + j * 128;
        vf4 v = *(const vf4*)(rb + k);
        int g = (spos >> 3) + 4 * j;
        h16x2 h01 = __builtin_amdgcn_cvt_pkrtz(v[0], v[1]);
        h16x2 h23 = __builtin_amdgcn_cvt_pkrtz(v[2], v[3]);
        h16x2 l01 = __builtin_amdgcn_cvt_pkrtz(v[0] - (float)h01[0], v[1] - (float)h01[1]);
        h16x2 l23 = __builtin_amdgcn_cvt_pkrtz(v[2] - (float)h23[0], v[3] - (float)h23[1]);
        h16x4 h4 = __builtin_shufflevector(h01, h23, 0, 1, 2, 3);
        h16x4 l4 = __builtin_shufflevector(l01, l23, 0, 1, 2, 3);
        int a = g * GSTR + srow * 40 + skk;
        *(h16x4*)(Ahi + a) = h4;
        *(h16x4*)(Alo + a) = l4;
      }
      if (s == 0 && tid < 256) {
        int r = tid >> 4, c0 = (tid & 15) * 4;
        vf4 a = *(const vf4*)(ss + ((size_t)(row0 + r) * TSTEPS + t) * 64 + c0);
        vf4 b = *(const vf4*)(us + ((size_t)(row0 + r) * TSTEPS + t) * 64 + c0);
        vf4 m = a + b;
        *(vf4*)&su[r * 68 + c0] = m;
      }
    }
    __syncthreads();  // barA
    __syncthreads();  // barB
    if (kh == 0) {
#pragma unroll
      for (int i = 0; i < 4; ++i)
        __hip_atomic_store(dummy + (lg * 4 + i) * 64 + n * 16 + l15, (unsigned)t,
                           __ATOMIC_RELAXED, __HIP_MEMORY_SCOPE_AGENT);
      asm volatile("s_waitcnt vmcnt(0)" ::: "memory");
      if (lane == 0) {
        unsigned old = atomicAdd(done, 1u);
        if (old == 4u * (unsigned)t + 3u)
          __hip_atomic_store(myslot, (unsigned)(t + 1), __ATOMIC_RELAXED,
                             __HIP_MEMORY_SCOPE_AGENT);
      }
    }
  }
}

__global__ __launch_bounds__(512, 2) void probe3_kernel(
    const float* __restrict__ x0, const float* __restrict__ ss,
    const float* __restrict__ us, const float* __restrict__ Bsm,
    const float* __restrict__ Wm, const float* __restrict__ bv,
    const float* __restrict__ xs, unsigned* __restrict__ flags, int slotoff)
{
  extern __shared__ char smem[];
  _Float16* Ahi = (_Float16*)smem;
  _Float16* Alo = (_Float16*)(smem + 41984);
  float* red = (float*)(smem + 83968);
  float* su = (float*)(smem + 88320);
  unsigned* done = (unsigned*)(smem + 92672);
  const int tid = threadIdx.x, lane = tid & 63, wave = tid >> 6;
  const int n = wave & 3, kh = wave >> 2;
  const int bid = blockIdx.x, jb = bid >> 3;
  const int c = (bid & 7) + 8 * (jb >> 4), s = jb & 15;
  const int l15 = lane & 15, lg = lane >> 4;
  const int row0 = c * 16, col0 = s * 64;
  const int jcol = col0 + n * 16 + l15;
  const int srow = tid >> 5, spos = tid & 31, skk = (tid & 7) * 4;
  unsigned* slotb = flags + slotoff;
  unsigned* myslot = slotb + c * 16 + s;
  unsigned* pollp  = slotb + c * 16 + l15;
  float* dummyf = (float*)(flags + 4096 + bid * 1024);

  f16x8 Whi[16], Wlo[16];
#pragma unroll
  for (int i = 0; i < 16; ++i) {
    int g = kh * 16 + i;
    const float* p = Wm + (size_t)jcol * 1024 + 32 * g + 8 * lg;
    vf4 v0 = *(const vf4*)p, v1 = *(const vf4*)(p + 4);
#pragma unroll
    for (int e = 0; e < 4; ++e) {
      float va = v0[e]; _Float16 h = (_Float16)va;
      Whi[i][e] = h; Wlo[i][e] = (_Float16)(va - (float)h);
      float vb = v1[e]; _Float16 h2 = (_Float16)vb;
      Whi[i][e + 4] = h2; Wlo[i][e + 4] = (_Float16)(vb - (float)h2);
    }
  }
  const float bcol = bv[jcol];
  f32x4 xold = {0.f, 0.f, 0.f, 0.f};
  if (kh == 0) {
#pragma unroll
    for (int i = 0; i < 4; ++i)
      xold[i] = x0[(size_t)(row0 + lg * 4 + i) * 1024 + jcol];
  }
  if (tid == 0) *done = 0u;
  __syncthreads();

  for (int t = 0; t < TSTEPS - 1; ++t) {
    if (t > 0) {
      if (wave == 4) {
        unsigned v;
        do {
          v = __hip_atomic_load(pollp, __ATOMIC_RELAXED, __HIP_MEMORY_SCOPE_AGENT);
        } while (!__all((int)(v >= (unsigned)t)));
      }
      __syncthreads();
    }
    asm volatile("" ::: "memory");
    {  // staging from t-VARYING xs (cold ceiling; real address stream)
      const float* rb = (t == 0)
          ? (x0 + (size_t)(row0 + srow) * 1024)
          : (xs + ((size_t)(row0 + srow) * TSTEPS + t) * 1024);
#pragma unroll
      for (int j = 0; j < 8; ++j) {
        int k = spos * 4 + j * 128;
        vf4 v = *(const vf4*)(rb + k);
        int g = (spos >> 3) + 4 * j;
        h16x2 h01 = __builtin_amdgcn_cvt_pkrtz(v[0], v[1]);
        h16x2 h23 = __builtin_amdgcn_cvt_pkrtz(v[2], v[3]);
        h16x2 l01 = __builtin_amdgcn_cvt_pkrtz(v[0] - (float)h01[0], v[1] - (float)h01[1]);
        h16x2 l23 = __builtin_amdgcn_cvt_pkrtz(v[2] - (float)h23[0], v[3] - (float)h23[1]);
        h16x4 h4 = __builtin_shufflevector(h01, h23, 0, 1, 2, 3);
        h16x4 l4 = __builtin_shufflevector(l01, l23, 0, 1, 2, 3);
        int a = g * GSTR + srow * 40 + skk;
        *(h16x4*)(Ahi + a) = h4;
        *(h16x4*)(Alo + a) = l4;
      }
      if (s == 0 && tid < 256) {
        int r = tid >> 4, c0 = (tid & 15) * 4;
        vf4 a = *(const vf4*)(ss + ((size_t)(row0 + r) * TSTEPS + t) * 64 + c0);
        vf4 b = *(const vf4*)(us + ((size_t)(row0 + r) * TSTEPS + t) * 64 + c0);
        vf4 m = a + b;
        *(vf4*)&su[r * 68 + c0] = m;
      }
    }
    __syncthreads();

    f32x4 a0 = {0.f,0.f,0.f,0.f}, a1 = {0.f,0.f,0.f,0.f}, a2 = {0.f,0.f,0.f,0.f};
#pragma unroll
    for (int i = 0; i < 16; ++i) {
      int g = kh * 16 + i;
      const int ab = g * GSTR + l15 * 40 + 8 * lg;
      f16x8 ah = *(const f16x8*)(Ahi + ab);
      f16x8 al = *(const f16x8*)(Alo + ab);
      a0 = __builtin_amdgcn_mfma_f32_16x16x32_f16(ah, Whi[i], a0, 0, 0, 0);
      a1 = __builtin_amdgcn_mfma_f32_16x16x32_f16(ah, Wlo[i], a1, 0, 0, 0);
      a2 = __builtin_amdgcn_mfma_f32_16x16x32_f16(al, Whi[i], a2, 0, 0, 0);
    }
    if (kh == 1) {
#pragma unroll
      for (int i = 0; i < 4; ++i)
        red[(n * 16 + lg * 4 + i) * 17 + l15] = a0[i] + a1[i] + a2[i];
    }
    __syncthreads();

    if (kh == 0) {
#pragma unroll
      for (int i = 0; i < 4; ++i) {
        int r = lg * 4 + i;
        float z = a0[i] + a1[i] + a2[i] + red[(n * 16 + r) * 17 + l15] + bcol;
        if (s == 0) z += su[r * 68 + n * 16 + l15];
        float e = exp2f(z * 2.885390081777927f);
        float rc = __builtin_amdgcn_rcpf(e + 1.0f);
        float xnew = fmaf(0.9f, xold[i], fmaf(-0.2f, rc, 0.1f));
        xold[i] = xnew;
        __hip_atomic_store((unsigned*)&dummyf[r * 64 + n * 16 + l15],
                           __float_as_uint(xnew), __ATOMIC_RELAXED,
                           __HIP_MEMORY_SCOPE_AGENT);
      }
      asm volatile("s_waitcnt vmcnt(0)" ::: "memory");
      if (lane == 0) {
        unsigned old = atomicAdd(done, 1u);
        if (old == 4u * (unsigned)t + 3u)
          __hip_atomic_store(myslot, (unsigned)(t + 1), __ATOMIC_RELAXED,
                             __HIP_MEMORY_SCOPE_AGENT);
      }
    }
  }
}

extern "C" void kernel_launch(void* const* d_in, const int* in_sizes, int n_in,
                              void* d_out, int out_size, void* d_ws, size_t ws_size,
                              hipStream_t stream) {
  const float* x0 = (const float*)d_in[0];
  const float* ss = (const float*)d_in[1];
  const float* us = (const float*)d_in[2];
  const float* Bs = (const float*)d_in[3];
  const float* W  = (const float*)d_in[4];
  const float* bv = (const float*)d_in[5];
  const float* Wy = (const float*)d_in[6];
  const float* by = (const float*)d_in[7];
  float* xs = (float*)d_out;
  float* ys = xs + (size_t)256 * TSTEPS * 1024;
  unsigned* flags = (unsigned*)d_ws;

  (void)hipMemsetAsync(d_ws, 0, 6144, stream);

  (void)hipFuncSetAttribute(reinterpret_cast<const void*>(scan_kernel),
                            hipFuncAttributeMaxDynamicSharedMemorySize, SCAN_LDS);

  scan_kernel<<<dim3(256), dim3(512), SCAN_LDS, stream>>>(
      x0, ss, us, Bs, W, bv, xs, flags);
  y_kernel<<<dim3(1024, 4), dim3(256), 0, stream>>>(xs, Wy, by, ys);

  // diagnostic probes (write only d_ws); gated on workspace size
  if (ws_size >= (size_t)(16384 + 256 * 1024 * 4)) {
    (void)hipFuncSetAttribute(reinterpret_cast<const void*>(probe01_kernel),
                              hipFuncAttributeMaxDynamicSharedMemorySize, SCAN_LDS);
    (void)hipFuncSetAttribute(reinterpret_cast<const void*>(probe2_kernel),
                              hipFuncAttributeMaxDynamicSharedMemorySize, SCAN_LDS);
    (void)hipFuncSetAttribute(reinterpret_cast<const void*>(probe3_kernel),
                              hipFuncAttributeMaxDynamicSharedMemorySize, SCAN_LDS);
    probe01_kernel<<<dim3(256), dim3(512), SCAN_LDS, stream>>>(flags, 256, 0);
    probe01_kernel<<<dim3(256), dim3(512), SCAN_LDS, stream>>>(flags, 512, 1);
    probe2_kernel<<<dim3(256), dim3(512), SCAN_LDS, stream>>>(
        x0, ss, us, xs, flags, 768);
    probe3_kernel<<<dim3(256), dim3(512), SCAN_LDS, stream>>>(
        x0, ss, us, Bs, W, bv, xs, flags, 1024);
  }
}

// Round 10
// 1478.178 us; speedup vs baseline: 2.8863x; 2.8863x over previous
//
#include <hip/hip_runtime.h>
#include <hip/hip_fp16.h>
#include <math.h>

// RNN scan: x_{t+1} = 0.9 x_t + 0.1 tanh(W x_t + pad(s_t) + pad(u_t) + b)
// 16 clusters x 16 WGs; W in registers/AGPRs (f16 hi/lo, 3-MFMA compensated).
// R10: barrier-free split-phase pipeline. kh0 waves (0-3) depend only on
// x cols 0..511 (producers s=0..7); kh1 waves (4-7) only on cols 512..1023
// (s=8..15). Two concurrent delegate polls (wave0: slots 0-7, wave4: 8-15);
// per-half staging+MFMA; monotonic LDS semaphores replace all per-step
// __syncthreads; red/su double-buffered so kh1 runs ahead into step t+1.

#define TSTEPS 256

typedef _Float16 f16x8 __attribute__((ext_vector_type(8)));
typedef __fp16 h16x2 __attribute__((ext_vector_type(2)));
typedef __fp16 h16x4 __attribute__((ext_vector_type(4)));
typedef float f32x4 __attribute__((ext_vector_type(4)));
typedef float vf4 __attribute__((ext_vector_type(4)));
typedef float vf2 __attribute__((ext_vector_type(2)));

#define GSTR 656          // f16 units per kstep block (1312 B)
// LDS: Ahi 32*1312=41984 @0 ; Alo @41984 ; red[2][64][17]f32 @83968 (8704) ;
//      su[2][16][68]f32 @92672 (8704) ; sems[8] u32 @101376
#define SCAN_LDS 101408

// sems indices: 0=sem0(half0 ready) 1=sem1(half1 ready) 2=sA0(kh0 staged)
// 3=sA1(kh1 staged) 4=semN(kh0 mfma done) 5=semM(kh1 mfma+red done) 6=done(vote)

__device__ __forceinline__ void lds_spin(unsigned* p, unsigned tgt) {
  while (__hip_atomic_load(p, __ATOMIC_ACQUIRE, __HIP_MEMORY_SCOPE_WORKGROUP) < tgt) {}
}
__device__ __forceinline__ void lds_add1(unsigned* p) {
  __hip_atomic_fetch_add(p, 1u, __ATOMIC_RELEASE, __HIP_MEMORY_SCOPE_WORKGROUP);
}

__global__ __launch_bounds__(512, 2) void scan_kernel(
    const float* __restrict__ x0, const float* __restrict__ ss,
    const float* __restrict__ us, const float* __restrict__ Bsm,
    const float* __restrict__ Wm, const float* __restrict__ bv,
    float* __restrict__ xs, unsigned* __restrict__ flags)
{
  extern __shared__ char smem[];
  _Float16* Ahi = (_Float16*)smem;
  _Float16* Alo = (_Float16*)(smem + 41984);
  float* red = (float*)(smem + 83968);     // [2][64][17]
  float* su  = (float*)(smem + 92672);     // [2][16][68]
  unsigned* sems = (unsigned*)(smem + 101376);

  const int tid  = threadIdx.x;
  const int lane = tid & 63;
  const int wave = tid >> 6;        // 0..7
  const int n    = wave & 3;        // N-tile (16 cols)
  const int kh   = wave >> 2;       // K-half
  const int bid  = blockIdx.x;
  const int jb   = bid >> 3;
  const int c    = (bid & 7) + 8 * (jb >> 4);   // cluster 0..15
  const int s    = jb & 15;                     // WG within cluster
  const int row0 = c * 16;
  const int col0 = s * 64;

  const int l15 = lane & 15;
  const int lg  = lane >> 4;
  const int jcol = col0 + n * 16 + l15;

  // ---- preload W slice (f16 hi/lo): 16 ksteps x 8 elems per lane ----
  f16x8 Whi[16], Wlo[16];
#pragma unroll
  for (int i = 0; i < 16; ++i) {
    int g = kh * 16 + i;
    const float* p = Wm + (size_t)jcol * 1024 + 32 * g + 8 * lg;
    vf4 v0 = *(const vf4*)p, v1 = *(const vf4*)(p + 4);
#pragma unroll
    for (int e = 0; e < 4; ++e) {
      float va = v0[e]; _Float16 h = (_Float16)va;
      Whi[i][e] = h; Wlo[i][e] = (_Float16)(va - (float)h);
      float vb = v1[e]; _Float16 h2 = (_Float16)vb;
      Whi[i][e + 4] = h2; Wlo[i][e + 4] = (_Float16)(vb - (float)h2);
    }
  }

  const float bcol = bv[jcol];

  f32x4 xold = {0.f, 0.f, 0.f, 0.f};
  if (kh == 0) {
#pragma unroll
    for (int i = 0; i < 4; ++i)
      xold[i] = x0[(size_t)(row0 + lg * 4 + i) * 1024 + jcol];
  }

  // ---- x_seq[:,0,:] = x0 (own tile) ----
  {
    int i0 = tid * 2; int r = i0 >> 6, cc = i0 & 63;
    *(vf2*)&xs[((size_t)(row0 + r) * TSTEPS) * 1024 + col0 + cc] =
        *(const vf2*)&x0[(size_t)(row0 + r) * 1024 + col0 + cc];
  }
  if (tid < 8) sems[tid] = 0u;
  __syncthreads();   // the only full barrier: sems initialized

  unsigned* const myslot = flags + c * 16 + s;

  // staging geometry: 256 threads per half, 8 x float4 per thread (32 KB)
  const int hx   = tid & 255;        // index within my half's 256 threads
  const int srow = hx >> 4;          // 0..15
  const int spos = hx & 15;
  const int skk  = (spos & 7) * 4;

  for (int t = 0; t < TSTEPS - 1; ++t) {
    const unsigned ut = (unsigned)t;

    if (kh == 0) {
      // ---- discovery of half-0 (cols 0..511, producers s=0..7) ----
      if (wave == 0) {
        if (t > 0) {
          bool rdy;
          do {
            unsigned v = 0xFFFFFFFFu;
            if (lane < 8)
              v = __hip_atomic_load(flags + c * 16 + lane, __ATOMIC_RELAXED,
                                    __HIP_MEMORY_SCOPE_AGENT);
            rdy = __all((int)(v >= ut));
          } while (!rdy);
        }
        if (lane == 0) lds_add1(&sems[0]);
      } else {
        lds_spin(&sems[0], ut + 1u);
      }
      asm volatile("" ::: "memory");
      if (t > 0) lds_spin(&sems[4], 4u * ut);   // all kh0 MFMA(t-1) done

      // ---- stage half-0: ksteps 0..15 ----
      {
        const float* rb = (t == 0)
            ? (x0 + (size_t)(row0 + srow) * 1024)
            : (xs + ((size_t)(row0 + srow) * TSTEPS + t) * 1024);
#pragma unroll
        for (int j = 0; j < 8; ++j) {
          int k = spos * 4 + j * 64;
          vf4 v = *(const vf4*)(rb + k);
          int g = (spos >> 3) + 2 * j;
          h16x2 h01 = __builtin_amdgcn_cvt_pkrtz(v[0], v[1]);
          h16x2 h23 = __builtin_amdgcn_cvt_pkrtz(v[2], v[3]);
          h16x2 l01 = __builtin_amdgcn_cvt_pkrtz(v[0] - (float)h01[0],
                                                 v[1] - (float)h01[1]);
          h16x2 l23 = __builtin_amdgcn_cvt_pkrtz(v[2] - (float)h23[0],
                                                 v[3] - (float)h23[1]);
          h16x4 h4 = __builtin_shufflevector(h01, h23, 0, 1, 2, 3);
          h16x4 l4 = __builtin_shufflevector(l01, l23, 0, 1, 2, 3);
          int a = g * GSTR + srow * 40 + skk;
          *(h16x4*)(Ahi + a) = h4;
          *(h16x4*)(Alo + a) = l4;
        }
        if (s == 0) {   // drive s_t + u_t (cols 0..63), double-buffered
          int r = hx >> 4, c0 = (hx & 15) * 4;
          vf4 a = *(const vf4*)(ss + ((size_t)(row0 + r) * TSTEPS + t) * 64 + c0);
          vf4 b = *(const vf4*)(us + ((size_t)(row0 + r) * TSTEPS + t) * 64 + c0);
          vf4 m = a + b;
          *(vf4*)&su[(t & 1) * 1088 + r * 68 + c0] = m;
        }
      }
      if (lane == 0) lds_add1(&sems[2]);
      lds_spin(&sems[2], 4u * (ut + 1u));   // all kh0 staged

      // ---- MFMA ksteps 0..15 ----
      f32x4 a0 = {0.f,0.f,0.f,0.f}, a1 = {0.f,0.f,0.f,0.f}, a2 = {0.f,0.f,0.f,0.f};
#pragma unroll
      for (int i = 0; i < 16; ++i) {
        const int ab = i * GSTR + l15 * 40 + 8 * lg;
        f16x8 ah = *(const f16x8*)(Ahi + ab);
        f16x8 al = *(const f16x8*)(Alo + ab);
        a0 = __builtin_amdgcn_mfma_f32_16x16x32_f16(ah, Whi[i], a0, 0, 0, 0);
        a1 = __builtin_amdgcn_mfma_f32_16x16x32_f16(ah, Wlo[i], a1, 0, 0, 0);
        a2 = __builtin_amdgcn_mfma_f32_16x16x32_f16(al, Whi[i], a2, 0, 0, 0);
      }
      if (lane == 0) lds_add1(&sems[4]);          // semN
      lds_spin(&sems[5], 4u * (ut + 1u));         // wait kh1 red(t)

      // ---- epilogue ----
      const float* redb = red + (t & 1) * 1088;
      const float* sub  = su  + (t & 1) * 1088;
#pragma unroll
      for (int i = 0; i < 4; ++i) {
        int r = lg * 4 + i;
        float z = a0[i] + a1[i] + a2[i] + redb[(n * 16 + r) * 17 + l15] + bcol;
        if (s == 0) z += sub[r * 68 + n * 16 + l15];
        float e = exp2f(z * 2.885390081777927f);
        float rc = __builtin_amdgcn_rcpf(e + 1.0f);
        float xnew = fmaf(0.9f, xold[i], fmaf(-0.2f, rc, 0.1f));
        xold[i] = xnew;
        __hip_atomic_store(&xs[((size_t)(row0 + r) * TSTEPS + (t + 1)) * 1024 + jcol],
                           xnew, __ATOMIC_RELAXED, __HIP_MEMORY_SCOPE_AGENT);
      }
      asm volatile("s_waitcnt vmcnt(0)" ::: "memory");  // x stores agent-visible
      if (lane == 0) {
        unsigned old = __hip_atomic_fetch_add(&sems[6], 1u, __ATOMIC_RELAXED,
                                              __HIP_MEMORY_SCOPE_WORKGROUP);
        if (old == 4u * ut + 3u)
          __hip_atomic_store(myslot, ut + 1u, __ATOMIC_RELAXED,
                             __HIP_MEMORY_SCOPE_AGENT);
      }
    } else {
      // ---- discovery of half-1 (cols 512..1023, producers s=8..15) ----
      if (wave == 4) {
        if (t > 0) {
          bool rdy;
          do {
            unsigned v = 0xFFFFFFFFu;
            if (lane < 8)
              v = __hip_atomic_load(flags + c * 16 + 8 + lane, __ATOMIC_RELAXED,
                                    __HIP_MEMORY_SCOPE_AGENT);
            rdy = __all((int)(v >= ut));
          } while (!rdy);
        }
        if (lane == 0) lds_add1(&sems[1]);
      } else {
        lds_spin(&sems[1], ut + 1u);
      }
      asm volatile("" ::: "memory");
      if (t > 0) lds_spin(&sems[5], 4u * ut);   // all kh1 MFMA(t-1) done

      // ---- stage half-1: ksteps 16..31 ----
      {
        const float* rb = (t == 0)
            ? (x0 + (size_t)(row0 + srow) * 1024)
            : (xs + ((size_t)(row0 + srow) * TSTEPS + t) * 1024);
#pragma unroll
        for (int j = 0; j < 8; ++j) {
          int k = 512 + spos * 4 + j * 64;
          vf4 v = *(const vf4*)(rb + k);
          int g = 16 + (spos >> 3) + 2 * j;
          h16x2 h01 = __builtin_amdgcn_cvt_pkrtz(v[0], v[1]);
          h16x2 h23 = __builtin_amdgcn_cvt_pkrtz(v[2], v[3]);
          h16x2 l01 = __builtin_amdgcn_cvt_pkrtz(v[0] - (float)h01[0],
                                                 v[1] - (float)h01[1]);
          h16x2 l23 = __builtin_amdgcn_cvt_pkrtz(v[2] - (float)h23[0],
                                                 v[3] - (float)h23[1]);
          h16x4 h4 = __builtin_shufflevector(h01, h23, 0, 1, 2, 3);
          h16x4 l4 = __builtin_shufflevector(l01, l23, 0, 1, 2, 3);
          int a = g * GSTR + srow * 40 + skk;
          *(h16x4*)(Ahi + a) = h4;
          *(h16x4*)(Alo + a) = l4;
        }
      }
      if (lane == 0) lds_add1(&sems[3]);
      lds_spin(&sems[3], 4u * (ut + 1u));   // all kh1 staged

      // ---- MFMA ksteps 16..31, publish partials into red[t&1] ----
      f32x4 a0 = {0.f,0.f,0.f,0.f}, a1 = {0.f,0.f,0.f,0.f}, a2 = {0.f,0.f,0.f,0.f};
#pragma unroll
      for (int i = 0; i < 16; ++i) {
        const int ab = (16 + i) * GSTR + l15 * 40 + 8 * lg;
        f16x8 ah = *(const f16x8*)(Ahi + ab);
        f16x8 al = *(const f16x8*)(Alo + ab);
        a0 = __builtin_amdgcn_mfma_f32_16x16x32_f16(ah, Whi[i], a0, 0, 0, 0);
        a1 = __builtin_amdgcn_mfma_f32_16x16x32_f16(ah, Wlo[i], a1, 0, 0, 0);
        a2 = __builtin_amdgcn_mfma_f32_16x16x32_f16(al, Whi[i], a2, 0, 0, 0);
      }
      float* redb = red + (t & 1) * 1088;
#pragma unroll
      for (int i = 0; i < 4; ++i)
        redb[(n * 16 + lg * 4 + i) * 17 + l15] = a0[i] + a1[i] + a2[i];
      if (lane == 0) lds_add1(&sems[5]);    // semM (release: red visible)
    }
  }
}

// ---- readout: y[bt, :] = x_seq[bt, :] @ Wy^T + by ----
__global__ __launch_bounds__(256, 2) void y_kernel(
    const float* __restrict__ xs, const float* __restrict__ Wy,
    const float* __restrict__ by, float* __restrict__ ys)
{
  __shared__ _Float16 Af[64][72];
  __shared__ _Float16 Bf[64][72];
  const int tid = threadIdx.x;
  const int lane = tid & 63;
  const int wave = tid >> 6;
  const int l15 = lane & 15, lg = lane >> 4;
  const size_t bm = (size_t)blockIdx.x * 64;
  const int bn = blockIdx.y * 64;

  f32x4 acc[4];
#pragma unroll
  for (int q = 0; q < 4; ++q) acc[q] = (f32x4){0.f, 0.f, 0.f, 0.f};

  for (int kc = 0; kc < 16; ++kc) {
#pragma unroll
    for (int p = 0; p < 4; ++p) {
      int fi = tid + 256 * p;
      int r = fi >> 4, kq = fi & 15;
      vf4 va = *(const vf4*)(xs + (bm + r) * 1024 + kc * 64 + kq * 4);
      h16x2 a01 = __builtin_amdgcn_cvt_pkrtz(va[0], va[1]);
      h16x2 a23 = __builtin_amdgcn_cvt_pkrtz(va[2], va[3]);
      *(h16x4*)(&Af[r][kq * 4]) = __builtin_shufflevector(a01, a23, 0, 1, 2, 3);
      vf4 vb = *(const vf4*)(Wy + (size_t)(bn + r) * 1024 + kc * 64 + kq * 4);
      h16x2 b01 = __builtin_amdgcn_cvt_pkrtz(vb[0], vb[1]);
      h16x2 b23 = __builtin_amdgcn_cvt_pkrtz(vb[2], vb[3]);
      *(h16x4*)(&Bf[r][kq * 4]) = __builtin_shufflevector(b01, b23, 0, 1, 2, 3);
    }
    __syncthreads();
#pragma unroll
    for (int ks = 0; ks < 2; ++ks) {
      int k0 = ks * 32 + 8 * lg;
      f16x8 af = *(const f16x8*)(&Af[wave * 16 + l15][k0]);
#pragma unroll
      for (int nt = 0; nt < 4; ++nt) {
        f16x8 bf = *(const f16x8*)(&Bf[nt * 16 + l15][k0]);
        acc[nt] = __builtin_amdgcn_mfma_f32_16x16x32_f16(af, bf, acc[nt], 0, 0, 0);
      }
    }
    __syncthreads();
  }
#pragma unroll
  for (int nt = 0; nt < 4; ++nt) {
#pragma unroll
    for (int i = 0; i < 4; ++i) {
      size_t grow = bm + wave * 16 + lg * 4 + i;
      int gcol = bn + nt * 16 + l15;
      ys[grow * 256 + gcol] = acc[nt][i] + by[gcol];
    }
  }
}

extern "C" void kernel_launch(void* const* d_in, const int* in_sizes, int n_in,
                              void* d_out, int out_size, void* d_ws, size_t ws_size,
                              hipStream_t stream) {
  const float* x0 = (const float*)d_in[0];
  const float* ss = (const float*)d_in[1];
  const float* us = (const float*)d_in[2];
  const float* Bs = (const float*)d_in[3];
  const float* W  = (const float*)d_in[4];
  const float* bv = (const float*)d_in[5];
  const float* Wy = (const float*)d_in[6];
  const float* by = (const float*)d_in[7];
  float* xs = (float*)d_out;
  float* ys = xs + (size_t)256 * TSTEPS * 1024;
  unsigned* flags = (unsigned*)d_ws;

  // zero the 16*16 flag slots every call (graph-capture-safe)
  (void)hipMemsetAsync(d_ws, 0, 4096, stream);

  (void)hipFuncSetAttribute(reinterpret_cast<const void*>(scan_kernel),
                            hipFuncAttributeMaxDynamicSharedMemorySize, SCAN_LDS);

  scan_kernel<<<dim3(256), dim3(512), SCAN_LDS, stream>>>(
      x0, ss, us, Bs, W, bv, xs, flags);
  y_kernel<<<dim3(1024, 4), dim3(256), 0, stream>>>(xs, Wy, by, ys);
}